// Round 1
// baseline (222.899 us; speedup 1.0000x reference)
//
#include <hip/hip_runtime.h>

// GCN layer: out = (D^-1/2 (A+I) D^-1/2) X W^T + b
// N=100000, E=1600000, D=64.
//
// Round 12: eliminate the bucket_scale pass (D3). It re-read fp32 yf
// (25.6MB) + grec (6.4MB) and wrote yh (12.8MB) -- ~45MB + a dispatch --
// solely because deg wasn't known when the gemm epilogue ran. New: a tiny
// deg pre-pass (reads dst half of ei, 6.4MB, atomics into 400KB
// L2-resident deg[]) runs BEFORE the fused kernel, so the gemm epilogue
// applies rsqrt(deg+1) itself and emits bf16 yh directly (halves its
// store traffic; fp32 yf never materializes). csr_gather is unchanged --
// it derives the dst-side scale from its own bucket CSR as before.
// Output is bit-identical to round 11 (same deg ints, same accumulation,
// same f2b_rn rounding point).
//
// Pipeline (4 dispatches, one fewer heavyweight):
//   D0 memset gcur+deg (403KB)
//   D1 deg: atomicAdd over dst row of ei
//   D2 fused: gemm yh = bf16(xW^T * rsqrt(deg+1)) || binned scatter
//   D3 csr_gather: per-bucket LDS sort + gather pre-scaled rows + bias

#define BSHIFT 7
#define BNODES 128
#define CAP 3072   // records per bucket region (mean 2046, P(overflow)~1e-90)
#define EPB 4096   // edges per scatter block -> 391 blocks
#define SMEM_BYTES 32768  // max(gemm 32768, scatter 24576+nbuck*8<=30832)

__device__ inline unsigned short f2b_rn(float f) {
    unsigned u = __float_as_uint(f);
    unsigned r = u + 0x7FFFu + ((u >> 16) & 1u);
    return (unsigned short)(r >> 16);
}
__device__ inline float b2f(unsigned short h) {
    return __uint_as_float(((unsigned)h) << 16);
}

// --- D1: in-degree via scatter-add of ones onto dst (L2-resident table) ---
__global__ __launch_bounds__(256) void deg_kernel(
    const int* __restrict__ dst, int* __restrict__ deg, int e) {
    int t = blockIdx.x * blockDim.x + threadIdx.x;
    int stride = gridDim.x * blockDim.x;
    int e4 = e >> 2;
    const int4* d4 = (const int4*)dst;
    for (int i = t; i < e4; i += stride) {
        int4 v = d4[i];
        atomicAdd(&deg[v.x], 1);
        atomicAdd(&deg[v.y], 1);
        atomicAdd(&deg[v.z], 1);
        atomicAdd(&deg[v.w], 1);
    }
    for (int i = (e4 << 2) + t; i < e; i += stride)
        atomicAdd(&deg[dst[i]], 1);
}

// --- D2: fused gemm || scatter (independent work, one dispatch) ---
__global__ __launch_bounds__(256) void fused_gemm_scatter_kernel(
    const float* __restrict__ x, const float* __restrict__ W,
    ushort4* __restrict__ yh, const int* __restrict__ deg,
    const int* __restrict__ ei, int* __restrict__ gcur,
    unsigned int* __restrict__ grec,
    int n, int e, int nbuck, int sblocks) {
    __shared__ __align__(16) unsigned char smem[SMEM_BYTES];
    int t = threadIdx.x;

    if ((int)blockIdx.x < sblocks) {
        // ---- binned scatter into fixed-capacity bucket regions ----
        unsigned int* lrec = (unsigned int*)smem;               // EPB*4 = 16384
        unsigned short* lbk = (unsigned short*)(smem + 16384);  // EPB*2 = 8192
        int* lh = (int*)(smem + 24576);                         // [nbuck]
        int* lbase = lh + nbuck;                                // [nbuck]
        for (int i = t; i < nbuck; i += 256) lh[i] = 0;
        __syncthreads();
        int e0 = blockIdx.x * EPB;
        int m = e - e0;
        if (m > EPB) m = EPB;
        for (int i = t; i < m; i += 256) {
            int g = e0 + i;
            int s = ei[g];
            int d = ei[e + g];
            int b = d >> BSHIFT;
            lrec[i] = ((unsigned int)s << BSHIFT) | (unsigned int)(d & (BNODES - 1));
            lbk[i] = (unsigned short)b;
            atomicAdd(&lh[b], 1);
        }
        __syncthreads();
        for (int b = t; b < nbuck; b += 256) {
            int c = lh[b];
            lbase[b] = c ? atomicAdd(&gcur[b], c) : 0;
            lh[b] = 0;  // reuse as local cursor
        }
        __syncthreads();
        for (int i = t; i < m; i += 256) {
            int b = lbk[i];
            int pos = lbase[b] + atomicAdd(&lh[b], 1);
            if (pos < CAP)
                grec[(size_t)b * CAP + pos] = lrec[i];
        }
    } else {
        // ---- gemm: y = x @ W^T, scaled bf16 out; XOR-swizzled f4 LDS tiles --
        float4* At4 = (float4*)smem;             // [64*16] At4[k*16 + (r^(k&15))] = A[4r..+3][k]
        float4* Wt4 = (float4*)(smem + 16384);   // [64*16] same layout for W
        int m0 = ((int)blockIdx.x - sblocks) * 64;

#pragma unroll
        for (int j = 0; j < 4; ++j) {
            int idx = t + j * 256;      // 0..1023
            int k = idx & 63;           // lane-consecutive -> coalesced global
            int r = idx >> 6;           // quad row index 0..15
            // W tile: rows 4r..4r+3 at col k
            float4 wv;
            wv.x = W[(size_t)(4 * r + 0) * 64 + k];
            wv.y = W[(size_t)(4 * r + 1) * 64 + k];
            wv.z = W[(size_t)(4 * r + 2) * 64 + k];
            wv.w = W[(size_t)(4 * r + 3) * 64 + k];
            Wt4[k * 16 + (r ^ (k & 15))] = wv;
            // A tile: rows m0+4r..+3 at col k (guarded)
            float4 av;
            int gm = m0 + 4 * r;
            av.x = (gm + 0 < n) ? x[(size_t)(gm + 0) * 64 + k] : 0.f;
            av.y = (gm + 1 < n) ? x[(size_t)(gm + 1) * 64 + k] : 0.f;
            av.z = (gm + 2 < n) ? x[(size_t)(gm + 2) * 64 + k] : 0.f;
            av.w = (gm + 3 < n) ? x[(size_t)(gm + 3) * 64 + k] : 0.f;
            At4[k * 16 + (r ^ (k & 15))] = av;
        }
        __syncthreads();

        int tx = t & 15, ty = t >> 4;  // tx: out quad, ty: row quad
        float acc[4][4];
#pragma unroll
        for (int i = 0; i < 4; ++i)
#pragma unroll
            for (int j = 0; j < 4; ++j) acc[i][j] = 0.f;

#pragma unroll 8
        for (int k = 0; k < 64; ++k) {
            float4 a = At4[k * 16 + (ty ^ (k & 15))];  // rows ty*4..+3 @ k (broadcast)
            float4 w = Wt4[k * 16 + (tx ^ (k & 15))];  // cols tx*4..+3 @ k
            float av[4] = {a.x, a.y, a.z, a.w};
            float wv[4] = {w.x, w.y, w.z, w.w};
#pragma unroll
            for (int i = 0; i < 4; ++i)
#pragma unroll
                for (int j = 0; j < 4; ++j) acc[i][j] += av[i] * wv[j];
        }

        // epilogue: src-side normalization + bf16 pack (deg load broadcasts
        // across the 16 tx lanes of a row)
#pragma unroll
        for (int i = 0; i < 4; ++i) {
            int gm = m0 + ty * 4 + i;
            if (gm < n) {
                float dn = rsqrtf((float)(deg[gm] + 1));  // +1 self loop
                ushort4 h;
                h.x = f2b_rn(acc[i][0] * dn);
                h.y = f2b_rn(acc[i][1] * dn);
                h.z = f2b_rn(acc[i][2] * dn);
                h.w = f2b_rn(acc[i][3] * dn);
                yh[(size_t)gm * 16 + tx] = h;
            }
        }
    }
}

// --- D3: per-bucket fused sort + gather (512 thr: 782 blocks all-resident) ---
__global__ __launch_bounds__(512, 4) void csr_gather_kernel(
    const unsigned int* __restrict__ grec, const int* __restrict__ gcur,
    const ushort4* __restrict__ yh, const float* __restrict__ bias,
    float4* __restrict__ out, int n) {
    __shared__ unsigned int sorted[CAP];  // 12288 B: src ids grouped by dst
    __shared__ int lh[BNODES];            // hist, then cursor
    __shared__ int ls[BNODES + 1];        // exclusive offsets; ls[128] = cnt
    __shared__ int wtot;
    int t = threadIdx.x;
    int b = blockIdx.x;
    size_t base = (size_t)b * CAP;
    int cnt = gcur[b];
    if (cnt > CAP) cnt = CAP;
    int node0 = b << BSHIFT;

    if (t < BNODES) lh[t] = 0;
    __syncthreads();
    for (int i = t; i < cnt; i += 512)
        atomicAdd(&lh[grec[base + i] & (BNODES - 1)], 1);
    __syncthreads();
    int c = 0, ex = 0;
    if (t < BNODES) {  // waves 0,1: inclusive shfl scan over 128 bins
        c = lh[t];
        int lane64 = t & 63;
        int v = c;
#pragma unroll
        for (int o = 1; o < 64; o <<= 1) {
            int u = __shfl_up(v, o, 64);
            if (lane64 >= o) v += u;
        }
        if (t == 63) wtot = v;
        ex = v - c;
    }
    __syncthreads();
    if (t >= 64 && t < BNODES) ex += wtot;
    if (t < BNODES) {
        ls[t] = ex;
        lh[t] = 0;  // cursor
        if (t == BNODES - 1) ls[BNODES] = ex + c;
    }
    __syncthreads();
    for (int i = t; i < cnt; i += 512) {  // re-read grec (L2-hot), sort into LDS
        unsigned int r = grec[base + i];
        int nd = r & (BNODES - 1);
        int pos = ls[nd] + atomicAdd(&lh[nd], 1);
        sorted[pos] = r >> BSHIFT;
    }
    __syncthreads();

    // ---- gather: wave w handles nodes [w*16, w*16+16) of this bucket ----
    int wave = t >> 6;
    int lane = t & 63;
    int grp = lane >> 4;   // which of 4 concurrent edges
    int fq = lane & 15;    // feature quad
    float4 bb = ((const float4*)bias)[fq];
    for (int i = 0; i < 16; ++i) {
        int nd = wave * 16 + i;
        int node = node0 + nd;
        if (node >= n) break;  // uniform per wave
        int beg = ls[nd];
        int end = ls[nd + 1];
        float dn = rsqrtf((float)(end - beg) + 1.0f);  // deg+1 (self loop)
        float4 acc = {0.f, 0.f, 0.f, 0.f};
        if (grp == 0) {  // self loop term y'_self
            ushort4 h = yh[(size_t)node * 16 + fq];
            acc.x = b2f(h.x); acc.y = b2f(h.y);
            acc.z = b2f(h.z); acc.w = b2f(h.w);
        }
        int j = beg + grp;
        // 4x unrolled: four independent row loads in flight per iteration
        for (; j + 12 < end; j += 16) {
            int s0 = (int)sorted[j];
            int s1 = (int)sorted[j + 4];
            int s2 = (int)sorted[j + 8];
            int s3 = (int)sorted[j + 12];
            ushort4 h0 = yh[(size_t)s0 * 16 + fq];  // 128B rows
            ushort4 h1 = yh[(size_t)s1 * 16 + fq];
            ushort4 h2 = yh[(size_t)s2 * 16 + fq];
            ushort4 h3 = yh[(size_t)s3 * 16 + fq];
            acc.x += b2f(h0.x) + b2f(h1.x) + b2f(h2.x) + b2f(h3.x);
            acc.y += b2f(h0.y) + b2f(h1.y) + b2f(h2.y) + b2f(h3.y);
            acc.z += b2f(h0.z) + b2f(h1.z) + b2f(h2.z) + b2f(h3.z);
            acc.w += b2f(h0.w) + b2f(h1.w) + b2f(h2.w) + b2f(h3.w);
        }
        for (; j < end; j += 4) {  // tail, one per group-stride
            int s = (int)sorted[j];
            ushort4 h = yh[(size_t)s * 16 + fq];
            acc.x += b2f(h.x); acc.y += b2f(h.y);
            acc.z += b2f(h.z); acc.w += b2f(h.w);
        }
        for (int m = 16; m < 64; m <<= 1) {  // reduce 4 edge-groups
            acc.x += __shfl_xor(acc.x, m);
            acc.y += __shfl_xor(acc.y, m);
            acc.z += __shfl_xor(acc.z, m);
            acc.w += __shfl_xor(acc.w, m);
        }
        if (lane < 16) {
            float4 o;
            o.x = acc.x * dn + bb.x;
            o.y = acc.y * dn + bb.y;
            o.z = acc.z * dn + bb.z;
            o.w = acc.w * dn + bb.w;
            out[(size_t)node * 16 + lane] = o;
        }
    }
}

extern "C" void kernel_launch(void* const* d_in, const int* in_sizes, int n_in,
                              void* d_out, int out_size, void* d_ws, size_t ws_size,
                              hipStream_t stream) {
    const float* x    = (const float*)d_in[0];
    const int*   ei   = (const int*)d_in[1];  // [2,E]: src row then dst row
    const float* W    = (const float*)d_in[2];
    const float* bias = (const float*)d_in[3];
    float* out = (float*)d_out;

    int n = in_sizes[0] / 64;
    int e = in_sizes[1] / 2;
    int nbuck = (n + BNODES - 1) / BNODES;  // 782 (<=1024 for scatter smem carve)

    // workspace (256B aligned): gcur | deg | grec | yh  (~23 MB)
    auto align = [](size_t v) { return (v + 255) & ~(size_t)255; };
    char* p = (char*)d_ws;
    int* gcur = (int*)p;          p += align((size_t)nbuck * 4);
    int* deg = (int*)p;           p += align((size_t)n * 4);
    unsigned int* grec = (unsigned int*)p;  p += align((size_t)nbuck * CAP * 4);
    ushort4* yh = (ushort4*)p;

    int sblocks = (e + EPB - 1) / EPB;   // 391
    int gblocks = (n + 63) / 64;         // 1563

    // zero gcur + deg in one contiguous memset (they're adjacent)
    hipMemsetAsync(gcur, 0, (char*)grec - (char*)gcur, stream);
    deg_kernel<<<1024, 256, 0, stream>>>(ei + e, deg, e);
    fused_gemm_scatter_kernel<<<sblocks + gblocks, 256, 0, stream>>>(
        x, W, yh, deg, ei, gcur, grec, n, e, nbuck, sblocks);
    csr_gather_kernel<<<nbuck, 512, 0, stream>>>(grec, gcur, yh, bias,
                                                 (float4*)out, n);
}

// Round 2
// 172.051 us; speedup vs baseline: 1.2955x; 1.2955x over previous
//
#include <hip/hip_runtime.h>

// GCN layer: out = (D^-1/2 (A+I) D^-1/2) X W^T + b
// N=100000, E=1600000, D=64.
//
// Round 13: post-mortem of r12 -- global-atomic deg_kernel cost 67us
// (WRITE_SIZE 49.9MB = 1.6M atomics x 32B write-through sectors; random
// 4B atomics run at the ~810GB/s scattered-write ceiling). Revert to
// LDS-hist deg, but WITHOUT round-11's 70MB yf round-trip:
//   - scatter runs first (standalone);
//   - the GEMM kernel hists its own bucket's grec records (L2/L3-hot,
//     ~1KB) into LDS, then applies rsqrt(deg+1) in the epilogue and
//     writes bf16 yh directly. No deg array, no extra pass.
// Also: BNODES 128->64. csr_gather was 49% occupancy (782 x 512thr,
// 2 blocks/CU resident -> straggler tail). 1563 x 256thr blocks with
// __launch_bounds__(256,8) are fully co-resident; scan becomes a single
// wave; bucket == one 64-row GEMM tile.
//
// Pipeline (4 dispatches):
//   D0 memset gcur (6KB)
//   D1 scatter: bin edges into fixed-capacity bucket regions
//   D2 gemm_scaled: per-bucket LDS deg hist + xW^T + bf16(acc*rsqrt(deg+1))
//   D3 csr_gather: per-bucket LDS sort + gather pre-scaled rows + bias

#define BSHIFT 6
#define BNODES 64
#define CAP 1536      // records per bucket (mean 1024, +16 sigma)
#define EPB 4096      // edges per scatter block -> 391 blocks
#define NBUCK_PAD 1568  // >= nbuck (1563), for static smem carve

__device__ inline unsigned short f2b_rn(float f) {
    unsigned u = __float_as_uint(f);
    unsigned r = u + 0x7FFFu + ((u >> 16) & 1u);
    return (unsigned short)(r >> 16);
}
__device__ inline float b2f(unsigned short h) {
    return __uint_as_float(((unsigned)h) << 16);
}

// --- D1: binned scatter into fixed-capacity bucket regions ---
__global__ __launch_bounds__(256) void scatter_kernel(
    const int* __restrict__ ei, int* __restrict__ gcur,
    unsigned int* __restrict__ grec, int e, int nbuck) {
    __shared__ unsigned int lrec[EPB];       // 16384 B
    __shared__ unsigned short lbk[EPB];      //  8192 B
    __shared__ int lh[NBUCK_PAD];            //  6272 B
    __shared__ int lbase[NBUCK_PAD];         //  6272 B
    int t = threadIdx.x;
    for (int i = t; i < nbuck; i += 256) lh[i] = 0;
    __syncthreads();
    int e0 = blockIdx.x * EPB;
    int m = e - e0;
    if (m > EPB) m = EPB;
    for (int i = t; i < m; i += 256) {
        int g = e0 + i;
        int s = ei[g];
        int d = ei[e + g];
        int b = d >> BSHIFT;
        lrec[i] = ((unsigned int)s << BSHIFT) | (unsigned int)(d & (BNODES - 1));
        lbk[i] = (unsigned short)b;
        atomicAdd(&lh[b], 1);
    }
    __syncthreads();
    for (int b = t; b < nbuck; b += 256) {
        int c = lh[b];
        lbase[b] = c ? atomicAdd(&gcur[b], c) : 0;
        lh[b] = 0;  // reuse as local cursor
    }
    __syncthreads();
    for (int i = t; i < m; i += 256) {
        int b = lbk[i];
        int pos = lbase[b] + atomicAdd(&lh[b], 1);
        if (pos < CAP)
            grec[(size_t)b * CAP + pos] = lrec[i];
    }
}

// --- D2: per-bucket deg hist (from grec, L2-hot) + gemm + scaled bf16 out ---
// Block b handles rows [64b, 64b+64): y = x @ W^T, yh = bf16(y * rsqrt(deg+1))
__global__ __launch_bounds__(256) void gemm_scaled_kernel(
    const float* __restrict__ x, const float* __restrict__ W,
    ushort4* __restrict__ yh,
    const unsigned int* __restrict__ grec, const int* __restrict__ gcur,
    int n) {
    __shared__ __align__(16) float4 At4[1024];  // At4[k*16+(r^(k&15))]=A[4r..+3][k]
    __shared__ __align__(16) float4 Wt4[1024];  // same swizzle for W
    __shared__ int lh[BNODES];
    int t = threadIdx.x;
    int b = blockIdx.x;
    int m0 = b << BSHIFT;

    if (t < BNODES) lh[t] = 0;
    __syncthreads();

    // deg hist for this bucket: ~1024 records, contiguous, L2/L3-hot
    size_t base = (size_t)b * CAP;
    int cnt = gcur[b];
    if (cnt > CAP) cnt = CAP;
    for (int i = t; i < cnt; i += 256)
        atomicAdd(&lh[grec[base + i] & (BNODES - 1)], 1);

    // stage tiles (XOR-swizzled float4 quads; lane-consecutive-k coalesced)
#pragma unroll
    for (int j = 0; j < 4; ++j) {
        int idx = t + j * 256;      // 0..1023
        int k = idx & 63;
        int r = idx >> 6;           // quad row index 0..15
        float4 wv;
        wv.x = W[(size_t)(4 * r + 0) * 64 + k];
        wv.y = W[(size_t)(4 * r + 1) * 64 + k];
        wv.z = W[(size_t)(4 * r + 2) * 64 + k];
        wv.w = W[(size_t)(4 * r + 3) * 64 + k];
        Wt4[k * 16 + (r ^ (k & 15))] = wv;
        float4 av;
        int gm = m0 + 4 * r;
        av.x = (gm + 0 < n) ? x[(size_t)(gm + 0) * 64 + k] : 0.f;
        av.y = (gm + 1 < n) ? x[(size_t)(gm + 1) * 64 + k] : 0.f;
        av.z = (gm + 2 < n) ? x[(size_t)(gm + 2) * 64 + k] : 0.f;
        av.w = (gm + 3 < n) ? x[(size_t)(gm + 3) * 64 + k] : 0.f;
        At4[k * 16 + (r ^ (k & 15))] = av;
    }
    __syncthreads();

    int tx = t & 15, ty = t >> 4;  // tx: out quad, ty: row quad
    float acc[4][4];
#pragma unroll
    for (int i = 0; i < 4; ++i)
#pragma unroll
        for (int j = 0; j < 4; ++j) acc[i][j] = 0.f;

#pragma unroll 8
    for (int k = 0; k < 64; ++k) {
        float4 a = At4[k * 16 + (ty ^ (k & 15))];  // rows ty*4..+3 @ k (broadcast)
        float4 w = Wt4[k * 16 + (tx ^ (k & 15))];  // cols tx*4..+3 @ k
        float av[4] = {a.x, a.y, a.z, a.w};
        float wv[4] = {w.x, w.y, w.z, w.w};
#pragma unroll
        for (int i = 0; i < 4; ++i)
#pragma unroll
            for (int j = 0; j < 4; ++j) acc[i][j] += av[i] * wv[j];
    }

    // epilogue: src-side normalization from LDS deg + bf16 pack
#pragma unroll
    for (int i = 0; i < 4; ++i) {
        int gm = m0 + ty * 4 + i;
        if (gm < n) {
            float dn = rsqrtf((float)(lh[ty * 4 + i] + 1));  // +1 self loop
            ushort4 h;
            h.x = f2b_rn(acc[i][0] * dn);
            h.y = f2b_rn(acc[i][1] * dn);
            h.z = f2b_rn(acc[i][2] * dn);
            h.w = f2b_rn(acc[i][3] * dn);
            yh[(size_t)gm * 16 + tx] = h;
        }
    }
}

// --- D3: per-bucket fused sort + gather (1563 x 256thr, fully resident) ---
__global__ __launch_bounds__(256, 8) void csr_gather_kernel(
    const unsigned int* __restrict__ grec, const int* __restrict__ gcur,
    const ushort4* __restrict__ yh, const float* __restrict__ bias,
    float4* __restrict__ out, int n) {
    __shared__ unsigned int sorted[CAP];  // 6144 B: src ids grouped by dst
    __shared__ int lh[BNODES];            // hist, then cursor
    __shared__ int ls[BNODES + 1];        // exclusive offsets; ls[64] = cnt
    int t = threadIdx.x;
    int b = blockIdx.x;
    size_t base = (size_t)b * CAP;
    int cnt = gcur[b];
    if (cnt > CAP) cnt = CAP;
    int node0 = b << BSHIFT;

    if (t < BNODES) lh[t] = 0;
    __syncthreads();
    for (int i = t; i < cnt; i += 256)
        atomicAdd(&lh[grec[base + i] & (BNODES - 1)], 1);
    __syncthreads();
    if (t < BNODES) {  // wave 0: inclusive shfl scan over 64 bins
        int c = lh[t];
        int v = c;
#pragma unroll
        for (int o = 1; o < 64; o <<= 1) {
            int u = __shfl_up(v, o, 64);
            if (t >= o) v += u;
        }
        ls[t] = v - c;
        lh[t] = 0;  // cursor
        if (t == 63) ls[BNODES] = v;
    }
    __syncthreads();
    for (int i = t; i < cnt; i += 256) {  // re-read grec (L2-hot), sort into LDS
        unsigned int r = grec[base + i];
        int nd = r & (BNODES - 1);
        int pos = ls[nd] + atomicAdd(&lh[nd], 1);
        sorted[pos] = r >> BSHIFT;
    }
    __syncthreads();

    // ---- gather: wave w handles nodes [w*16, w*16+16) of this bucket ----
    int wave = t >> 6;
    int lane = t & 63;
    int grp = lane >> 4;   // which of 4 concurrent edges
    int fq = lane & 15;    // feature quad
    float4 bb = ((const float4*)bias)[fq];
    for (int i = 0; i < 16; ++i) {
        int nd = wave * 16 + i;
        int node = node0 + nd;
        if (node >= n) break;  // uniform per wave
        int beg = ls[nd];
        int end = ls[nd + 1];
        float dn = rsqrtf((float)(end - beg) + 1.0f);  // deg+1 (self loop)
        float4 acc = {0.f, 0.f, 0.f, 0.f};
        if (grp == 0) {  // self loop term y'_self
            ushort4 h = yh[(size_t)node * 16 + fq];
            acc.x = b2f(h.x); acc.y = b2f(h.y);
            acc.z = b2f(h.z); acc.w = b2f(h.w);
        }
        int j = beg + grp;
        // 4x unrolled: four independent row loads in flight per iteration
        for (; j + 12 < end; j += 16) {
            int s0 = (int)sorted[j];
            int s1 = (int)sorted[j + 4];
            int s2 = (int)sorted[j + 8];
            int s3 = (int)sorted[j + 12];
            ushort4 h0 = yh[(size_t)s0 * 16 + fq];  // 128B rows
            ushort4 h1 = yh[(size_t)s1 * 16 + fq];
            ushort4 h2 = yh[(size_t)s2 * 16 + fq];
            ushort4 h3 = yh[(size_t)s3 * 16 + fq];
            acc.x += b2f(h0.x) + b2f(h1.x) + b2f(h2.x) + b2f(h3.x);
            acc.y += b2f(h0.y) + b2f(h1.y) + b2f(h2.y) + b2f(h3.y);
            acc.z += b2f(h0.z) + b2f(h1.z) + b2f(h2.z) + b2f(h3.z);
            acc.w += b2f(h0.w) + b2f(h1.w) + b2f(h2.w) + b2f(h3.w);
        }
        for (; j < end; j += 4) {  // tail, one per group-stride
            int s = (int)sorted[j];
            ushort4 h = yh[(size_t)s * 16 + fq];
            acc.x += b2f(h.x); acc.y += b2f(h.y);
            acc.z += b2f(h.z); acc.w += b2f(h.w);
        }
        for (int m = 16; m < 64; m <<= 1) {  // reduce 4 edge-groups
            acc.x += __shfl_xor(acc.x, m);
            acc.y += __shfl_xor(acc.y, m);
            acc.z += __shfl_xor(acc.z, m);
            acc.w += __shfl_xor(acc.w, m);
        }
        if (lane < 16) {
            float4 o;
            o.x = acc.x * dn + bb.x;
            o.y = acc.y * dn + bb.y;
            o.z = acc.z * dn + bb.z;
            o.w = acc.w * dn + bb.w;
            out[(size_t)node * 16 + lane] = o;
        }
    }
}

extern "C" void kernel_launch(void* const* d_in, const int* in_sizes, int n_in,
                              void* d_out, int out_size, void* d_ws, size_t ws_size,
                              hipStream_t stream) {
    const float* x    = (const float*)d_in[0];
    const int*   ei   = (const int*)d_in[1];  // [2,E]: src row then dst row
    const float* W    = (const float*)d_in[2];
    const float* bias = (const float*)d_in[3];
    float* out = (float*)d_out;

    int n = in_sizes[0] / 64;
    int e = in_sizes[1] / 2;
    int nbuck = (n + BNODES - 1) / BNODES;  // 1563 (<= NBUCK_PAD)

    // workspace (256B aligned): gcur | grec | yh  (~23 MB)
    auto align = [](size_t v) { return (v + 255) & ~(size_t)255; };
    char* p = (char*)d_ws;
    int* gcur = (int*)p;                    p += align((size_t)nbuck * 4);
    unsigned int* grec = (unsigned int*)p;  p += align((size_t)nbuck * CAP * 4);
    ushort4* yh = (ushort4*)p;

    int sblocks = (e + EPB - 1) / EPB;   // 391

    hipMemsetAsync(gcur, 0, (size_t)nbuck * 4, stream);
    scatter_kernel<<<sblocks, 256, 0, stream>>>(ei, gcur, grec, e, nbuck);
    gemm_scaled_kernel<<<nbuck, 256, 0, stream>>>(x, W, yh, grec, gcur, n);
    csr_gather_kernel<<<nbuck, 256, 0, stream>>>(grec, gcur, yh, bias,
                                                 (float4*)out, n);
}